// Round 11
// baseline (100.243 us; speedup 1.0000x reference)
//
#include <hip/hip_runtime.h>
#include <hip/hip_bf16.h>

#define N_      2048
#define TWO_N   4096
#define DFEAT   128
#define SCALE   2.0f                   // 1 / TEMPERATURE
#define BROWS   128                    // rows per block  (4 waves x 32)
#define BCOLS   128                    // cols per block (LDS-staged panel)
#define NT      (BCOLS / 16)           // 8 column-tiles per panel
#define LDSTR   132                    // shorts per col (264 B): conflict-free quads
#define NBLK    1024                   // simsum grid size (32 x 32)

typedef __attribute__((ext_vector_type(8))) short bf16x8;
typedef __attribute__((ext_vector_type(4))) float f32x4;

// ---------------------------------------------------------------------------
// Kernel 1 (fused prep), 1024 blocks x 256 thr (4 waves = 4 rows per block):
//   row < N : normalize anchor row -> zn16[row], AND dvec[row] = 2*cos(a,neg)
//   row >= N: normalize pos row   -> zn16[row]
//   Zero-inits accS[4096] / accP[2048] and the completion counter.
// ---------------------------------------------------------------------------
__global__ __launch_bounds__(256) void k_prep(const float* __restrict__ a,
                                              const float* __restrict__ p,
                                              const float* __restrict__ ng,
                                              __hip_bfloat16* __restrict__ zn16,
                                              float* __restrict__ dvec,
                                              float* __restrict__ accS,
                                              float* __restrict__ accP,
                                              unsigned int* __restrict__ counter) {
  const int wave = threadIdx.x >> 6;
  const int lane = threadIdx.x & 63;
  const int row  = blockIdx.x * 4 + wave;   // 0..4095

  // zero atomic accumulators: 4 accS + 2 accP entries per block, + counter
  if (threadIdx.x < 4)        accS[blockIdx.x * 4 + threadIdx.x] = 0.0f;
  else if (threadIdx.x < 6)   accP[blockIdx.x * 2 + threadIdx.x - 4] = 0.0f;
  if (blockIdx.x == 0 && threadIdx.x == 6) counter[0] = 0u;

  if (row < N_) {
    float2 u = ((const float2*)(a  + (size_t)row * DFEAT))[lane];
    float2 w = ((const float2*)(ng + (size_t)row * DFEAT))[lane];
    float saa = u.x * u.x + u.y * u.y;
    float snn = w.x * w.x + w.y * w.y;
    float san = u.x * w.x + u.y * w.y;
#pragma unroll
    for (int m = 1; m < 64; m <<= 1) {
      saa += __shfl_xor(saa, m);
      snn += __shfl_xor(snn, m);
      san += __shfl_xor(san, m);
    }
    float na = fmaxf(sqrtf(saa), 1e-8f);
    float rn = 1.0f / na;
    __hip_bfloat162 h;
    h.x = __float2bfloat16(u.x * rn);
    h.y = __float2bfloat16(u.y * rn);
    ((__hip_bfloat162*)zn16)[row * (DFEAT / 2) + lane] = h;
    if (lane == 0)
      dvec[row] = SCALE * san / (na * fmaxf(sqrtf(snn), 1e-8f));
  } else {
    float2 v = ((const float2*)(p + (size_t)(row - N_) * DFEAT))[lane];
    float ss = v.x * v.x + v.y * v.y;
#pragma unroll
    for (int m = 1; m < 64; m <<= 1) ss += __shfl_xor(ss, m);
    float rn = 1.0f / fmaxf(sqrtf(ss), 1e-8f);
    __hip_bfloat162 h;
    h.x = __float2bfloat16(v.x * rn);
    h.y = __float2bfloat16(v.y * rn);
    ((__hip_bfloat162*)zn16)[row * (DFEAT / 2) + lane] = h;
  }
}

// ---------------------------------------------------------------------------
// Kernel 2 (R10 structure + block-class epilogue + fused last-block finalize)
//   grid = (32 row strips x 32 col chunks) = 1024 blocks, 256 thr (4 waves),
//   4 blocks/CU, balanced. Block classes (uniform branch, per blockIdx):
//     DIAG     by==bx            : exclude c==r,       -> accS
//     PARTLO   bx<16, by==bx+16  : exclude c==r+N,     -> accS
//     BOUND    bx>=16, by==bx-16 : exclude c==r-N, split c<r-N ? accP : accS
//     ALLP     bx>=16, by<bx-16  :                     -> accP
//     GENS     otherwise         :                     -> accS
//   Generic epilogue = mul+exp+add per entry. Last-arriving block finalizes
//   (R3/R9-verified fence + agent-scope counter protocol).
// ---------------------------------------------------------------------------
__global__ __launch_bounds__(256) void k_simsum(const __hip_bfloat16* __restrict__ zn16,
                                                const float* __restrict__ dvec,
                                                float* __restrict__ accS,
                                                float* __restrict__ accP,
                                                unsigned int* __restrict__ counter,
                                                float* __restrict__ out) {
  __shared__ __align__(16) short Bp[BCOLS * LDSTR];   // 33792 B
  __shared__ float red[4];
  __shared__ unsigned int slast;

  const int bx = blockIdx.x, by = blockIdx.y;
  const int wave = threadIdx.x >> 6;
  const int lane = threadIdx.x & 63;
  const int lr   = lane & 15;
  const int kg   = lane >> 4;
  const int rows_base = bx * BROWS + wave * 32;
  const int cb0 = by * BCOLS;
  const short* zs = (const short*)zn16;

  const bool hi = (bx >= 16);
  // block class, uniform across the block
  const int cls = (by == bx) ? 0                       // DIAG
                : (!hi && by == bx + 16) ? 1           // PARTLO
                : (hi && by == bx - 16) ? 2            // BOUND
                : (hi && by < bx - 16) ? 3             // ALLP
                : 4;                                   // GENS

  // A fragments: two 16-row tiles (gathered once)
  bf16x8 a0[4], a1[4];
#pragma unroll
  for (int kk = 0; kk < 4; ++kk) {
    a0[kk] = *(const bf16x8*)(zs + (size_t)(rows_base + lr) * DFEAT + kk * 32 + kg * 8);
    a1[kk] = *(const bf16x8*)(zs + (size_t)(rows_base + 16 + lr) * DFEAT + kk * 32 + kg * 8);
  }

  // stage B panel: 128 cols x 256 B = 2048 16-B chunks, 256 thr -> 8 passes
#pragma unroll
  for (int it = 0; it < 8; ++it) {
    const int g   = it * 256 + threadIdx.x;
    const int col = g >> 4;
    const int q   = g & 15;
    bf16x8 v = *(const bf16x8*)(zs + (size_t)(cb0 + col) * DFEAT + q * 8);
    *(bf16x8*)(&Bp[col * LDSTR + q * 8]) = v;
  }
  __syncthreads();

  int rrow[2][4], excl[2][4];
#pragma unroll
  for (int t = 0; t < 2; ++t)
#pragma unroll
    for (int j = 0; j < 4; ++j) {
      rrow[t][j] = rows_base + t * 16 + kg * 4 + j;
      excl[t][j] = (cls == 0) ? rrow[t][j]
                 : (cls == 1) ? rrow[t][j] + N_
                 : (cls == 2) ? rrow[t][j] - N_ : -1;
    }

  float acc1v[2][4] = {{0.f,0.f,0.f,0.f},{0.f,0.f,0.f,0.f}};  // primary (S or P)
  float acc2v[2][4] = {{0.f,0.f,0.f,0.f},{0.f,0.f,0.f,0.f}};  // BOUND: prefix P

  // 2-stage register pipeline on B fragments
  bf16x8 bcur[4], bnxt[4];
#pragma unroll
  for (int kk = 0; kk < 4; ++kk)
    bcur[kk] = *(const bf16x8*)(&Bp[lr * LDSTR + kk * 32 + kg * 8]);

#pragma unroll 2
  for (int ct = 0; ct < NT; ++ct) {
    const int ctn = (ct + 1 < NT) ? (ct + 1) : ct;
#pragma unroll
    for (int kk = 0; kk < 4; ++kk)
      bnxt[kk] = *(const bf16x8*)(&Bp[(ctn * 16 + lr) * LDSTR + kk * 32 + kg * 8]);

    f32x4 acc0 = {0.f, 0.f, 0.f, 0.f};
    f32x4 acc1 = {0.f, 0.f, 0.f, 0.f};
#pragma unroll
    for (int kk = 0; kk < 4; ++kk) {
      acc0 = __builtin_amdgcn_mfma_f32_16x16x32_bf16(a0[kk], bcur[kk], acc0, 0, 0, 0);
      acc1 = __builtin_amdgcn_mfma_f32_16x16x32_bf16(a1[kk], bcur[kk], acc1, 0, 0, 0);
    }

    const int c = cb0 + ct * 16 + lr;
    if (cls == 4 || cls == 3) {
      // generic: no masks, single accumulator (S or P decided at flush)
#pragma unroll
      for (int j = 0; j < 4; ++j) {
        acc1v[0][j] += __expf(SCALE * acc0[j]);
        acc1v[1][j] += __expf(SCALE * acc1[j]);
      }
    } else if (cls == 2) {
      // hi boundary: exclude c==r-N, split prefix/suffix
#pragma unroll
      for (int j = 0; j < 4; ++j) {
        float e0 = __expf(SCALE * acc0[j]);
        e0 = (c == excl[0][j]) ? 0.0f : e0;
        if (c < excl[0][j]) acc2v[0][j] += e0; else acc1v[0][j] += e0;
        float e1 = __expf(SCALE * acc1[j]);
        e1 = (c == excl[1][j]) ? 0.0f : e1;
        if (c < excl[1][j]) acc2v[1][j] += e1; else acc1v[1][j] += e1;
      }
    } else {
      // DIAG / PARTLO: exclude one column, accS
#pragma unroll
      for (int j = 0; j < 4; ++j) {
        float e0 = __expf(SCALE * acc0[j]);
        acc1v[0][j] += (c == excl[0][j]) ? 0.0f : e0;
        float e1 = __expf(SCALE * acc1[j]);
        acc1v[1][j] += (c == excl[1][j]) ? 0.0f : e1;
      }
    }

#pragma unroll
    for (int kk = 0; kk < 4; ++kk) bcur[kk] = bnxt[kk];
  }

  // flush: reduce across the 16 lr lanes, one atomic per row per target
#pragma unroll
  for (int t = 0; t < 2; ++t)
#pragma unroll
    for (int j = 0; j < 4; ++j) {
      float v1 = acc1v[t][j], v2 = acc2v[t][j];
#pragma unroll
      for (int m = 1; m < 16; m <<= 1) {
        v1 += __shfl_xor(v1, m);
        if (cls == 2) v2 += __shfl_xor(v2, m);
      }
      if (lr == 0) {
        const int r = rrow[t][j];
        if (cls == 3)      atomicAdd(&accP[r - N_], v1);
        else               atomicAdd(&accS[r], v1);
        if (cls == 2)      atomicAdd(&accP[r - N_], v2);
      }
    }

  // ---- completion: release fence, count, last block finalizes ----
  __threadfence();
  __syncthreads();
  if (threadIdx.x == 0)
    slast = __hip_atomic_fetch_add(counter, 1u, __ATOMIC_ACQ_REL,
                                   __HIP_MEMORY_SCOPE_AGENT);
  __syncthreads();
  if (slast != NBLK - 1) return;
  __threadfence();   // acquire: see all blocks' accS/accP

  // ---------------- finalize (one block, 256 thr) ----------------
  const int tid = threadIdx.x;
  float dpart = 0.f;
  for (int i = tid; i < N_; i += 256) dpart += __expf(dvec[i]);
#pragma unroll
  for (int m = 1; m < 64; m <<= 1) dpart += __shfl_xor(dpart, m);
  if (lane == 0) red[wave] = dpart;
  __syncthreads();
  const float Dsum = red[0] + red[1] + red[2] + red[3];
  __syncthreads();

  float part = 0.f;
  for (int r = tid; r < TWO_N; r += 256) {
    float S = accS[r];
    float v;
    if (r < N_) {
      v = logf(2.0f * __expf(dvec[r]) + S) - dvec[r];
    } else {
      const int i = r - N_;
      const float extra = (i < N_ - 1) ? accP[i + 1] : Dsum;
      v = logf(__expf(dvec[i]) + S + extra) - dvec[i];
    }
    part += v;
  }
#pragma unroll
  for (int m = 1; m < 64; m <<= 1) part += __shfl_xor(part, m);
  if (lane == 0) red[wave] = part;
  __syncthreads();
  if (tid == 0)
    out[0] = (red[0] + red[1] + red[2] + red[3]) / (float)TWO_N;
}

// ---------------------------------------------------------------------------
extern "C" void kernel_launch(void* const* d_in, const int* in_sizes, int n_in,
                              void* d_out, int out_size, void* d_ws, size_t ws_size,
                              hipStream_t stream) {
  const float* a  = (const float*)d_in[0];
  const float* p  = (const float*)d_in[1];
  const float* ng = (const float*)d_in[2];

  char* ws = (char*)d_ws;
  __hip_bfloat16* zn16 = (__hip_bfloat16*)ws;                    // 1 MB
  float* dvec = (float*)(ws + (size_t)TWO_N * DFEAT * 2);        // 16 KB slot
  float* accS = dvec + TWO_N;                                    // 16 KB
  float* accP = accS + TWO_N;                                    // 8 KB
  unsigned int* counter = (unsigned int*)(accP + N_);

  k_prep<<<TWO_N / 4, 256, 0, stream>>>(a, p, ng, zn16, dvec, accS, accP, counter);
  k_simsum<<<dim3(TWO_N / BROWS, TWO_N / BCOLS), 256, 0, stream>>>(
      zn16, dvec, accS, accP, counter, (float*)d_out);
}

// Round 12
// 24.004 us; speedup vs baseline: 4.1761x; 4.1761x over previous
//
#include <hip/hip_runtime.h>
#include <hip/hip_bf16.h>

#define N_      2048
#define TWO_N   4096
#define DFEAT   128
#define SCALE   2.0f                   // 1 / TEMPERATURE
#define BROWS   128                    // rows per block  (4 waves x 32)
#define BCOLS   128                    // cols per block (LDS-staged panel)
#define NT      (BCOLS / 16)           // 8 column-tiles per panel
#define LDSTR   132                    // shorts per col (264 B)
#define SC_L2E  2.8853900817779268f    // SCALE * log2(e): exp(2x) = exp2(x*SC_L2E)

typedef __attribute__((ext_vector_type(8))) short bf16x8;
typedef __attribute__((ext_vector_type(4))) float f32x4;

// ---------------------------------------------------------------------------
// Kernel 1 (fused prep), 1024 blocks x 256 thr (4 waves = 4 rows per block):
//   row < N : normalize anchor row -> zn16[row], AND dvec[row] = 2*cos(a,neg)
//   row >= N: normalize pos row   -> zn16[row]
//   Also zero-inits the atomic accumulators accS[4096] / accP[2048].
// ---------------------------------------------------------------------------
__global__ __launch_bounds__(256) void k_prep(const float* __restrict__ a,
                                              const float* __restrict__ p,
                                              const float* __restrict__ ng,
                                              __hip_bfloat16* __restrict__ zn16,
                                              float* __restrict__ dvec,
                                              float* __restrict__ accS,
                                              float* __restrict__ accP) {
  const int wave = threadIdx.x >> 6;
  const int lane = threadIdx.x & 63;
  const int row  = blockIdx.x * 4 + wave;   // 0..4095

  // zero atomic accumulators: 4 accS + 2 accP entries per block
  if (threadIdx.x < 4)        accS[blockIdx.x * 4 + threadIdx.x] = 0.0f;
  else if (threadIdx.x < 6)   accP[blockIdx.x * 2 + threadIdx.x - 4] = 0.0f;

  if (row < N_) {
    float2 u = ((const float2*)(a  + (size_t)row * DFEAT))[lane];
    float2 w = ((const float2*)(ng + (size_t)row * DFEAT))[lane];
    float saa = u.x * u.x + u.y * u.y;
    float snn = w.x * w.x + w.y * w.y;
    float san = u.x * w.x + u.y * w.y;
#pragma unroll
    for (int m = 1; m < 64; m <<= 1) {
      saa += __shfl_xor(saa, m);
      snn += __shfl_xor(snn, m);
      san += __shfl_xor(san, m);
    }
    float na = fmaxf(sqrtf(saa), 1e-8f);
    float rn = 1.0f / na;
    __hip_bfloat162 h;
    h.x = __float2bfloat16(u.x * rn);
    h.y = __float2bfloat16(u.y * rn);
    ((__hip_bfloat162*)zn16)[row * (DFEAT / 2) + lane] = h;
    if (lane == 0)
      dvec[row] = SCALE * san / (na * fmaxf(sqrtf(snn), 1e-8f));
  } else {
    float2 v = ((const float2*)(p + (size_t)(row - N_) * DFEAT))[lane];
    float ss = v.x * v.x + v.y * v.y;
#pragma unroll
    for (int m = 1; m < 64; m <<= 1) ss += __shfl_xor(ss, m);
    float rn = 1.0f / fmaxf(sqrtf(ss), 1e-8f);
    __hip_bfloat162 h;
    h.x = __float2bfloat16(v.x * rn);
    h.y = __float2bfloat16(v.y * rn);
    ((__hip_bfloat162*)zn16)[row * (DFEAT / 2) + lane] = h;
  }
}

// ---------------------------------------------------------------------------
// Kernel 2 (R10 structure + block-class epilogue; NO fence/counter protocol —
//   that cost ~70 us in R3/R9/R11). grid = 32x32 = 1024 blocks, 256 thr
//   (4 waves), 4 blocks/CU, balanced. Block classes (uniform per blockIdx):
//     DIAG   by==bx           : exclude c==r,       -> accS
//     PARTLO bx<16, by==bx+16 : exclude c==r+N,     -> accS
//     BOUND  bx>=16, by==bx-16: exclude c==r-N, split c<r-N ? accP : accS
//     ALLP   bx>=16, by<bx-16 : mask-free           -> accP
//     GENS   otherwise        : mask-free           -> accS
//   Mask-free epilogue = exp2(acc*C) + add (26/32 of block-columns).
// ---------------------------------------------------------------------------
__global__ __launch_bounds__(256) void k_simsum(const __hip_bfloat16* __restrict__ zn16,
                                                float* __restrict__ accS,
                                                float* __restrict__ accP) {
  __shared__ __align__(16) short Bp[BCOLS * LDSTR];   // 33792 B

  const int bx = blockIdx.x, by = blockIdx.y;
  const int wave = threadIdx.x >> 6;
  const int lane = threadIdx.x & 63;
  const int lr   = lane & 15;
  const int kg   = lane >> 4;
  const int rows_base = bx * BROWS + wave * 32;
  const int cb0 = by * BCOLS;
  const short* zs = (const short*)zn16;

  const bool hi = (bx >= 16);
  const int cls = (by == bx) ? 0                       // DIAG
                : (!hi && by == bx + 16) ? 1           // PARTLO
                : (hi && by == bx - 16) ? 2            // BOUND
                : (hi && by < bx - 16) ? 3             // ALLP
                : 4;                                   // GENS

  // A fragments: two 16-row tiles (gathered once)
  bf16x8 a0[4], a1[4];
#pragma unroll
  for (int kk = 0; kk < 4; ++kk) {
    a0[kk] = *(const bf16x8*)(zs + (size_t)(rows_base + lr) * DFEAT + kk * 32 + kg * 8);
    a1[kk] = *(const bf16x8*)(zs + (size_t)(rows_base + 16 + lr) * DFEAT + kk * 32 + kg * 8);
  }

  // stage B panel: 128 cols x 256 B = 2048 16-B chunks, 256 thr -> 8 passes
#pragma unroll
  for (int it = 0; it < 8; ++it) {
    const int g   = it * 256 + threadIdx.x;
    const int col = g >> 4;
    const int q   = g & 15;
    bf16x8 v = *(const bf16x8*)(zs + (size_t)(cb0 + col) * DFEAT + q * 8);
    *(bf16x8*)(&Bp[col * LDSTR + q * 8]) = v;
  }
  __syncthreads();

  int rrow[2][4], excl[2][4];
#pragma unroll
  for (int t = 0; t < 2; ++t)
#pragma unroll
    for (int j = 0; j < 4; ++j) {
      rrow[t][j] = rows_base + t * 16 + kg * 4 + j;
      excl[t][j] = (cls == 0) ? rrow[t][j]
                 : (cls == 1) ? rrow[t][j] + N_
                 : (cls == 2) ? rrow[t][j] - N_ : -1;
    }

  float acc1v[2][4] = {{0.f,0.f,0.f,0.f},{0.f,0.f,0.f,0.f}};  // primary (S or P)
  float acc2v[2][4] = {{0.f,0.f,0.f,0.f},{0.f,0.f,0.f,0.f}};  // BOUND: prefix P

  // 2-stage register pipeline on B fragments
  bf16x8 bcur[4], bnxt[4];
#pragma unroll
  for (int kk = 0; kk < 4; ++kk)
    bcur[kk] = *(const bf16x8*)(&Bp[lr * LDSTR + kk * 32 + kg * 8]);

#pragma unroll 2
  for (int ct = 0; ct < NT; ++ct) {
    const int ctn = (ct + 1 < NT) ? (ct + 1) : ct;
#pragma unroll
    for (int kk = 0; kk < 4; ++kk)
      bnxt[kk] = *(const bf16x8*)(&Bp[(ctn * 16 + lr) * LDSTR + kk * 32 + kg * 8]);

    f32x4 acc0 = {0.f, 0.f, 0.f, 0.f};
    f32x4 acc1 = {0.f, 0.f, 0.f, 0.f};
#pragma unroll
    for (int kk = 0; kk < 4; ++kk) {
      acc0 = __builtin_amdgcn_mfma_f32_16x16x32_bf16(a0[kk], bcur[kk], acc0, 0, 0, 0);
      acc1 = __builtin_amdgcn_mfma_f32_16x16x32_bf16(a1[kk], bcur[kk], acc1, 0, 0, 0);
    }

    const int c = cb0 + ct * 16 + lr;
    if (cls >= 3) {
      // mask-free: exp2 + add only (26/32 of block-columns)
#pragma unroll
      for (int j = 0; j < 4; ++j) {
        acc1v[0][j] += __builtin_amdgcn_exp2f(acc0[j] * SC_L2E);
        acc1v[1][j] += __builtin_amdgcn_exp2f(acc1[j] * SC_L2E);
      }
    } else if (cls == 2) {
      // hi boundary: exclude c==r-N, split prefix/suffix
#pragma unroll
      for (int j = 0; j < 4; ++j) {
        float e0 = __builtin_amdgcn_exp2f(acc0[j] * SC_L2E);
        e0 = (c == excl[0][j]) ? 0.0f : e0;
        if (c < excl[0][j]) acc2v[0][j] += e0; else acc1v[0][j] += e0;
        float e1 = __builtin_amdgcn_exp2f(acc1[j] * SC_L2E);
        e1 = (c == excl[1][j]) ? 0.0f : e1;
        if (c < excl[1][j]) acc2v[1][j] += e1; else acc1v[1][j] += e1;
      }
    } else {
      // DIAG / PARTLO: exclude one column, accS
#pragma unroll
      for (int j = 0; j < 4; ++j) {
        float e0 = __builtin_amdgcn_exp2f(acc0[j] * SC_L2E);
        acc1v[0][j] += (c == excl[0][j]) ? 0.0f : e0;
        float e1 = __builtin_amdgcn_exp2f(acc1[j] * SC_L2E);
        acc1v[1][j] += (c == excl[1][j]) ? 0.0f : e1;
      }
    }

#pragma unroll
    for (int kk = 0; kk < 4; ++kk) bcur[kk] = bnxt[kk];
  }

  // flush: reduce across the 16 lr lanes, one atomic per row per target
#pragma unroll
  for (int t = 0; t < 2; ++t)
#pragma unroll
    for (int j = 0; j < 4; ++j) {
      float v1 = acc1v[t][j], v2 = acc2v[t][j];
#pragma unroll
      for (int m = 1; m < 16; m <<= 1) {
        v1 += __shfl_xor(v1, m);
        if (cls == 2) v2 += __shfl_xor(v2, m);
      }
      if (lr == 0) {
        const int r = rrow[t][j];
        if (cls == 3)      atomicAdd(&accP[r - N_], v1);
        else               atomicAdd(&accS[r], v1);
        if (cls == 2)      atomicAdd(&accP[r - N_], v2);
      }
    }
}

// ---------------------------------------------------------------------------
// Kernel 3: finalize — reads only accS[4096], accP[2048], dvec[2048] (32 KB).
//   row i<N:        log(2*E[i] + S[i]) - d[i]
//   row N+i, i<N-1: log(E[i] + S[N+i] + accP[i+1]) - d[i]
//   row 2N-1:       log(E[N-1] + S[2N-1] + sum_j E[j]) - d[N-1]
// ---------------------------------------------------------------------------
__global__ __launch_bounds__(1024) void k_final(const float* __restrict__ dvec,
                                                const float* __restrict__ accS,
                                                const float* __restrict__ accP,
                                                float* __restrict__ out) {
  __shared__ float Elds[N_];
  __shared__ float red[16];
  const int tid = threadIdx.x;
  float dpart = 0.f;
  for (int i = tid; i < N_; i += 1024) {
    float E = __expf(dvec[i]);
    Elds[i] = E;
    dpart += E;
  }
#pragma unroll
  for (int m = 1; m < 64; m <<= 1) dpart += __shfl_xor(dpart, m);
  const int w = tid >> 6, l = tid & 63;
  if (l == 0) red[w] = dpart;
  __syncthreads();
  float Dsum = 0.f;
#pragma unroll
  for (int k = 0; k < 16; ++k) Dsum += red[k];
  __syncthreads();  // before reusing red[]

  float part = 0.f;
  for (int r = tid; r < TWO_N; r += 1024) {
    float S = accS[r];
    float t;
    if (r < N_) {
      t = logf(2.0f * Elds[r] + S) - dvec[r];
    } else {
      const int i = r - N_;
      const float extra = (i < N_ - 1) ? accP[i + 1] : Dsum;
      t = logf(Elds[i] + S + extra) - dvec[i];
    }
    part += t;
  }
#pragma unroll
  for (int m = 1; m < 64; m <<= 1) part += __shfl_xor(part, m);
  if (l == 0) red[w] = part;
  __syncthreads();
  if (tid == 0) {
    float tot = 0.f;
#pragma unroll
    for (int k = 0; k < 16; ++k) tot += red[k];
    out[0] = tot / (float)TWO_N;
  }
}

// ---------------------------------------------------------------------------
extern "C" void kernel_launch(void* const* d_in, const int* in_sizes, int n_in,
                              void* d_out, int out_size, void* d_ws, size_t ws_size,
                              hipStream_t stream) {
  const float* a  = (const float*)d_in[0];
  const float* p  = (const float*)d_in[1];
  const float* ng = (const float*)d_in[2];

  char* ws = (char*)d_ws;
  __hip_bfloat16* zn16 = (__hip_bfloat16*)ws;                    // 1 MB
  float* dvec = (float*)(ws + (size_t)TWO_N * DFEAT * 2);        // 16 KB slot
  float* accS = dvec + TWO_N;                                    // 16 KB
  float* accP = accS + TWO_N;                                    // 8 KB

  k_prep<<<TWO_N / 4, 256, 0, stream>>>(a, p, ng, zn16, dvec, accS, accP);
  k_simsum<<<dim3(TWO_N / BROWS, TWO_N / BCOLS), 256, 0, stream>>>(zn16, accS, accP);
  k_final<<<1, 1024, 0, stream>>>(dvec, accS, accP, (float*)d_out);
}